// Round 3
// baseline (4692.487 us; speedup 1.0000x reference)
//
#include <hip/hip_runtime.h>
#include <math.h>

namespace {

constexpr int T  = 4096;
constexpr int NB = 256;   // batch
constexpr int I  = 64;
constexpr int H  = 256;
constexpr int O  = 64;
constexpr int HP = 288;   // padded h buffer: addr(k) = k + (k>>5)*4

// 512 threads/block, one block per batch row, one barrier per time step.
// Stage A (h update): thread owns j in {jx, jx+128}, k in [q*64, q*64+64).
// Stage B (y proj, deferred 1 step): thread owns output o, k in [seg*32,+32).
// amdgpu_waves_per_eu(2,2): occupancy is structurally 2 waves/SIMD (grid = 1
// block/CU), so let the register allocator use the full 256-VGPR budget and
// keep all 192 weight floats in arch VGPRs (R2's launch_bounds capped at 128
// -> weights went to AGPRs -> +1 v_accvgpr_read per FMA -> 2x VALU ops).
__global__ __launch_bounds__(512)
__attribute__((amdgpu_waves_per_eu(2, 2))) void rnn_fused(
    const float* __restrict__ xin,   // [T,NB,I]
    const float* __restrict__ Wih,   // [H,I]
    const float* __restrict__ Whh,   // [H,H]
    const float* __restrict__ Who,   // [O,H]
    float* __restrict__ out)         // [T*NB*O] ++ [NB*H]
{
  const int b   = blockIdx.x;
  const int tid = threadIdx.x;
  const int jx  = tid >> 2;   // 0..127
  const int q   = tid & 3;    // k-quarter
  const int o   = tid >> 3;   // 0..63
  const int seg = tid & 7;    // k-slice for y

  __shared__ __align__(16) float hbuf[2][HP];
  __shared__ __align__(16) float x_s[2][I];

  // ---- resident weights (192 floats/thread) ----
  float whh[2][64];
#pragma unroll
  for (int jj = 0; jj < 2; ++jj) {
    const float* r = Whh + (size_t)(jx + jj * 128) * H + q * 64;
#pragma unroll
    for (int c = 0; c < 16; ++c) {
      float4 v = *reinterpret_cast<const float4*>(r + c * 4);
      whh[jj][c*4+0] = v.x; whh[jj][c*4+1] = v.y;
      whh[jj][c*4+2] = v.z; whh[jj][c*4+3] = v.w;
    }
  }
  float wih[2][16];
#pragma unroll
  for (int jj = 0; jj < 2; ++jj) {
    const float* r = Wih + (size_t)(jx + jj * 128) * I + q * 16;
#pragma unroll
    for (int c = 0; c < 4; ++c) {
      float4 v = *reinterpret_cast<const float4*>(r + c * 4);
      wih[jj][c*4+0] = v.x; wih[jj][c*4+1] = v.y;
      wih[jj][c*4+2] = v.z; wih[jj][c*4+3] = v.w;
    }
  }
  float who[32];
  {
    const float* r = Who + (size_t)o * H + seg * 32;
#pragma unroll
    for (int c = 0; c < 8; ++c) {
      float4 v = *reinterpret_cast<const float4*>(r + c * 4);
      who[c*4+0] = v.x; who[c*4+1] = v.y; who[c*4+2] = v.z; who[c*4+3] = v.w;
    }
  }

  // ---- init: h(-1)=0, x(0) staged ----
  if (tid < HP) hbuf[0][tid] = 0.f;
  if (tid < 16) {
    float4 v = *reinterpret_cast<const float4*>(xin + (size_t)b * I + tid * 4);
    *reinterpret_cast<float4*>(&x_s[0][tid * 4]) = v;
  }
  __syncthreads();

  const int wj = jx + ((jx >> 5) << 2);            // padded addr of jx
  float* yp = out + (size_t)b * O + o;             // y(t) store cursor
  const float* xp = xin + (size_t)(NB * I) + (size_t)b * I + tid * 4;  // x(t+1)
  int p = 0;                                       // hbuf[p] = h(t-1)

  for (int t = 0; t < T; ++t) {
    // ---- deferred stage B: y(t-1) = h(t-1) @ Who^T ----
    if (t > 0) {
      const float* hb2 = &hbuf[p][seg * 36];   // padded addr of seg*32
      float y0 = 0.f, y1 = 0.f;
#pragma unroll
      for (int c = 0; c < 8; ++c) {
        float4 v = *reinterpret_cast<const float4*>(hb2 + c * 4);
        if (c & 1) {
          y1 = fmaf(v.x, who[c*4+0], y1); y1 = fmaf(v.y, who[c*4+1], y1);
          y1 = fmaf(v.z, who[c*4+2], y1); y1 = fmaf(v.w, who[c*4+3], y1);
        } else {
          y0 = fmaf(v.x, who[c*4+0], y0); y0 = fmaf(v.y, who[c*4+1], y0);
          y0 = fmaf(v.z, who[c*4+2], y0); y0 = fmaf(v.w, who[c*4+3], y0);
        }
      }
      float y = y0 + y1;
      y += __shfl_xor(y, 1);
      y += __shfl_xor(y, 2);
      y += __shfl_xor(y, 4);
      if (seg == 0) *yp = y;
      yp += NB * O;
    }

    // ---- x prefetch for t+1 ----
    float4 xpre;
    const bool pre = (t + 1 < T) && (tid < 16);
    if (pre) xpre = *reinterpret_cast<const float4*>(xp);
    xp += NB * I;

    // ---- stage A: h(t) = tanh(x(t)@Wih^T + h(t-1)@Whh^T) ----
    const float* hb = &hbuf[p][q * 72];      // padded addr of q*64
    const float* xb = &x_s[t & 1][q * 16];
    float a0 = 0.f, a1 = 0.f, a2 = 0.f, a3 = 0.f;
#pragma unroll
    for (int c = 0; c < 16; ++c) {
      const int m = c * 4;
      float4 hv = *reinterpret_cast<const float4*>(hb + m + ((m >= 32) ? 4 : 0));
      if (c & 1) {
        a1 = fmaf(hv.x, whh[0][m+0], a1); a1 = fmaf(hv.y, whh[0][m+1], a1);
        a1 = fmaf(hv.z, whh[0][m+2], a1); a1 = fmaf(hv.w, whh[0][m+3], a1);
        a3 = fmaf(hv.x, whh[1][m+0], a3); a3 = fmaf(hv.y, whh[1][m+1], a3);
        a3 = fmaf(hv.z, whh[1][m+2], a3); a3 = fmaf(hv.w, whh[1][m+3], a3);
      } else {
        a0 = fmaf(hv.x, whh[0][m+0], a0); a0 = fmaf(hv.y, whh[0][m+1], a0);
        a0 = fmaf(hv.z, whh[0][m+2], a0); a0 = fmaf(hv.w, whh[0][m+3], a0);
        a2 = fmaf(hv.x, whh[1][m+0], a2); a2 = fmaf(hv.y, whh[1][m+1], a2);
        a2 = fmaf(hv.z, whh[1][m+2], a2); a2 = fmaf(hv.w, whh[1][m+3], a2);
      }
    }
#pragma unroll
    for (int c = 0; c < 4; ++c) {
      float4 xv = *reinterpret_cast<const float4*>(xb + c * 4);
      a0 = fmaf(xv.x, wih[0][c*4+0], a0); a0 = fmaf(xv.y, wih[0][c*4+1], a0);
      a0 = fmaf(xv.z, wih[0][c*4+2], a0); a0 = fmaf(xv.w, wih[0][c*4+3], a0);
      a2 = fmaf(xv.x, wih[1][c*4+0], a2); a2 = fmaf(xv.y, wih[1][c*4+1], a2);
      a2 = fmaf(xv.z, wih[1][c*4+2], a2); a2 = fmaf(xv.w, wih[1][c*4+3], a2);
    }
    float s0 = a0 + a1, s1 = a2 + a3;
    s0 += __shfl_xor(s0, 1); s0 += __shfl_xor(s0, 2);
    s1 += __shfl_xor(s1, 1); s1 += __shfl_xor(s1, 2);

    s0 = fminf(fmaxf(s0, -15.f), 15.f);
    s1 = fminf(fmaxf(s1, -15.f), 15.f);
    const float e0 = __expf(2.f * s0);
    const float e1 = __expf(2.f * s1);
    const float h0 = 1.f - 2.f / (e0 + 1.f);
    const float h1 = 1.f - 2.f / (e1 + 1.f);

    float* hw = &hbuf[p ^ 1][0];
    if (q < 2) hw[wj + q * 144] = (q == 0) ? h0 : h1;  // q==1: padded jx+128

    if (pre) *reinterpret_cast<float4*>(&x_s[(t + 1) & 1][tid * 4]) = xpre;

    __syncthreads();
    p ^= 1;
  }

  // ---- tail: y(T-1) + h_last ----
  {
    const float* hb2 = &hbuf[p][seg * 36];
    float y0 = 0.f, y1 = 0.f;
#pragma unroll
    for (int c = 0; c < 8; ++c) {
      float4 v = *reinterpret_cast<const float4*>(hb2 + c * 4);
      if (c & 1) {
        y1 = fmaf(v.x, who[c*4+0], y1); y1 = fmaf(v.y, who[c*4+1], y1);
        y1 = fmaf(v.z, who[c*4+2], y1); y1 = fmaf(v.w, who[c*4+3], y1);
      } else {
        y0 = fmaf(v.x, who[c*4+0], y0); y0 = fmaf(v.y, who[c*4+1], y0);
        y0 = fmaf(v.z, who[c*4+2], y0); y0 = fmaf(v.w, who[c*4+3], y0);
      }
    }
    float y = y0 + y1;
    y += __shfl_xor(y, 1);
    y += __shfl_xor(y, 2);
    y += __shfl_xor(y, 4);
    if (seg == 0) *yp = y;
  }
  if (tid < H)
    out[(size_t)T * NB * O + (size_t)b * H + tid] = hbuf[p][tid + ((tid >> 5) << 2)];
}

}  // namespace

extern "C" void kernel_launch(void* const* d_in, const int* in_sizes, int n_in,
                              void* d_out, int out_size, void* d_ws, size_t ws_size,
                              hipStream_t stream) {
  const float* xin = (const float*)d_in[0];
  const float* Wih = (const float*)d_in[1];
  const float* Whh = (const float*)d_in[2];
  const float* Who = (const float*)d_in[3];
  float* out = (float*)d_out;
  hipLaunchKernelGGL(rnn_fused, dim3(NB), dim3(512), 0, stream,
                     xin, Wih, Whh, Who, out);
}

// Round 4
// 4571.014 us; speedup vs baseline: 1.0266x; 1.0266x over previous
//
#include <hip/hip_runtime.h>
#include <math.h>

namespace {

constexpr int T  = 4096;
constexpr int NB = 256;
constexpr int I  = 64;
constexpr int H  = 256;
constexpr int O  = 64;
constexpr int HPAD = 320;   // 256 floats padded: addr(k) = k + (k>>4)*4

// DPP row-rotate add: after ror 1,2,4,8 every lane of a 16-lane row holds the row sum.
template <int CTRL>
__device__ __forceinline__ float ror_add(float v) {
  int r = __builtin_amdgcn_update_dpp(0, __float_as_int(v), CTRL, 0xF, 0xF, true);
  return v + __int_as_float(r);
}
__device__ __forceinline__ float red16(float v) {
  v = ror_add<0x121>(v);  // row_ror:1
  v = ror_add<0x122>(v);  // row_ror:2
  v = ror_add<0x124>(v);  // row_ror:4
  v = ror_add<0x128>(v);  // row_ror:8
  return v;
}

__device__ __forceinline__ float tanh_fast(float s) {
  s = fminf(fmaxf(s, -15.f), 15.f);
  float e = __expf(2.f * s);
  return 1.f - 2.f / (e + 1.f);
}

// 1024 threads/block, one block per batch row, one barrier per step.
// kq = tid&15 (k-slice of 16), jg = tid>>4 (0..63).
// Thread rows: h-rows j = jg*4..+4, y-row o = jg; k-range = kq*16..+16.
// Weights: whh 64 + wih 16 + who 16 = 96 floats/thread -> fits 128-VGPR cap
// (4 waves/SIMD). y(t-1) = Who@h(t-1) shares the h LDS reads with the h-update.
__global__ __launch_bounds__(1024) void rnn_fused(
    const float* __restrict__ xin,   // [T,NB,I]
    const float* __restrict__ Wih,   // [H,I]
    const float* __restrict__ Whh,   // [H,H]
    const float* __restrict__ Who,   // [O,H]
    float* __restrict__ out)         // [T*NB*O] ++ [NB*H]
{
  const int b   = blockIdx.x;
  const int tid = threadIdx.x;
  const int kq  = tid & 15;
  const int jg  = tid >> 4;

  __shared__ __align__(16) float hbuf[2][HPAD];

  // ---- resident weights (96 floats) ----
  float whh[64];
#pragma unroll
  for (int jj = 0; jj < 4; ++jj) {
    const float* r = Whh + (size_t)(jg * 4 + jj) * H + kq * 16;
#pragma unroll
    for (int c = 0; c < 4; ++c) {
      float4 v = *reinterpret_cast<const float4*>(r + c * 4);
      whh[jj*16 + c*4 + 0] = v.x; whh[jj*16 + c*4 + 1] = v.y;
      whh[jj*16 + c*4 + 2] = v.z; whh[jj*16 + c*4 + 3] = v.w;
    }
  }
  float wih[16];
#pragma unroll
  for (int jj = 0; jj < 4; ++jj) {
    float4 v = *reinterpret_cast<const float4*>(Wih + (size_t)(jg * 4 + jj) * I + kq * 4);
    wih[jj*4 + 0] = v.x; wih[jj*4 + 1] = v.y;
    wih[jj*4 + 2] = v.z; wih[jj*4 + 3] = v.w;
  }
  float who[16];
  {
    const float* r = Who + (size_t)jg * H + kq * 16;
#pragma unroll
    for (int c = 0; c < 4; ++c) {
      float4 v = *reinterpret_cast<const float4*>(r + c * 4);
      who[c*4 + 0] = v.x; who[c*4 + 1] = v.y;
      who[c*4 + 2] = v.z; who[c*4 + 3] = v.w;
    }
  }

  // ---- init ----
  if (tid < HPAD) hbuf[0][tid] = 0.f;
  const float* xbase = xin + (size_t)b * I + kq * 4;       // + t*16384
  float4 xr = *reinterpret_cast<const float4*>(xbase);     // x(0) fragment
  const int ybase = b * O + jg;                            // + (t-1)*16384
  const int hwoff = (jg << 2) + ((jg >> 2) << 2);          // padded addr of j=jg*4
  __syncthreads();

  int p = 0;  // hbuf[p] = h(t-1)
  for (int t = 0; t < T; ++t) {
    // ---- ih part (consumes xr) ----
    float a0 = xr.x * wih[0];
    a0 = fmaf(xr.y, wih[1], a0);  a0 = fmaf(xr.z, wih[2],  a0);  a0 = fmaf(xr.w, wih[3],  a0);
    float a1 = xr.x * wih[4];
    a1 = fmaf(xr.y, wih[5], a1);  a1 = fmaf(xr.z, wih[6],  a1);  a1 = fmaf(xr.w, wih[7],  a1);
    float a2 = xr.x * wih[8];
    a2 = fmaf(xr.y, wih[9], a2);  a2 = fmaf(xr.z, wih[10], a2);  a2 = fmaf(xr.w, wih[11], a2);
    float a3 = xr.x * wih[12];
    a3 = fmaf(xr.y, wih[13], a3); a3 = fmaf(xr.z, wih[14], a3);  a3 = fmaf(xr.w, wih[15], a3);
    float ay = 0.f;

    // ---- prefetch x(t+1) early (drained by the end-of-step barrier) ----
    if (t + 1 < T)
      xr = *reinterpret_cast<const float4*>(xbase + ((size_t)(t + 1) << 14));

    // ---- hh + oh: 4 chunks of 4 h-values from LDS ----
    const float* hb = &hbuf[p][kq * 20];
#pragma unroll
    for (int c = 0; c < 4; ++c) {
      float4 hv = *reinterpret_cast<const float4*>(hb + c * 4);
      const int m = c * 4;
      a0 = fmaf(hv.x, whh[m+0],  a0); a0 = fmaf(hv.y, whh[m+1],  a0);
      a0 = fmaf(hv.z, whh[m+2],  a0); a0 = fmaf(hv.w, whh[m+3],  a0);
      a1 = fmaf(hv.x, whh[16+m+0], a1); a1 = fmaf(hv.y, whh[16+m+1], a1);
      a1 = fmaf(hv.z, whh[16+m+2], a1); a1 = fmaf(hv.w, whh[16+m+3], a1);
      a2 = fmaf(hv.x, whh[32+m+0], a2); a2 = fmaf(hv.y, whh[32+m+1], a2);
      a2 = fmaf(hv.z, whh[32+m+2], a2); a2 = fmaf(hv.w, whh[32+m+3], a2);
      a3 = fmaf(hv.x, whh[48+m+0], a3); a3 = fmaf(hv.y, whh[48+m+1], a3);
      a3 = fmaf(hv.z, whh[48+m+2], a3); a3 = fmaf(hv.w, whh[48+m+3], a3);
      ay = fmaf(hv.x, who[m+0],  ay); ay = fmaf(hv.y, who[m+1],  ay);
      ay = fmaf(hv.z, who[m+2],  ay); ay = fmaf(hv.w, who[m+3],  ay);
    }

    // ---- k-reduce (pure VALU, DPP row rotations) ----
    a0 = red16(a0); a1 = red16(a1); a2 = red16(a2); a3 = red16(a3);
    ay = red16(ay);

    // ---- activation + stores (lane kq==0 of each row) ----
    float4 hw;
    hw.x = tanh_fast(a0); hw.y = tanh_fast(a1);
    hw.z = tanh_fast(a2); hw.w = tanh_fast(a3);
    if (kq == 0) {
      *reinterpret_cast<float4*>(&hbuf[p ^ 1][hwoff]) = hw;
      if (t > 0) out[(size_t)ybase + ((size_t)(t - 1) << 14)] = ay;
    }

    __syncthreads();
    p ^= 1;
  }

  // ---- epilogue: y(T-1) + h_last ----
  {
    const float* hb = &hbuf[p][kq * 20];
    float ay = 0.f;
#pragma unroll
    for (int c = 0; c < 4; ++c) {
      float4 hv = *reinterpret_cast<const float4*>(hb + c * 4);
      const int m = c * 4;
      ay = fmaf(hv.x, who[m+0], ay); ay = fmaf(hv.y, who[m+1], ay);
      ay = fmaf(hv.z, who[m+2], ay); ay = fmaf(hv.w, who[m+3], ay);
    }
    ay = red16(ay);
    if (kq == 0) out[(size_t)ybase + ((size_t)(T - 1) << 14)] = ay;
  }
  if (tid < H)
    out[(size_t)T * NB * O + (size_t)b * H + tid] = hbuf[p][tid + ((tid >> 4) << 2)];
}

}  // namespace

extern "C" void kernel_launch(void* const* d_in, const int* in_sizes, int n_in,
                              void* d_out, int out_size, void* d_ws, size_t ws_size,
                              hipStream_t stream) {
  const float* xin = (const float*)d_in[0];
  const float* Wih = (const float*)d_in[1];
  const float* Whh = (const float*)d_in[2];
  const float* Who = (const float*)d_in[3];
  float* out = (float*)d_out;
  hipLaunchKernelGGL(rnn_fused, dim3(NB), dim3(1024), 0, stream,
                     xin, Wih, Whh, Who, out);
}

// Round 7
// 2908.075 us; speedup vs baseline: 1.6136x; 1.5718x over previous
//
#include <hip/hip_runtime.h>
#include <math.h>

namespace {

typedef __fp16 half2v __attribute__((ext_vector_type(2)));
static_assert(sizeof(half2v) == 4, "half2v must be 32-bit");

constexpr int T = 4096, NB = 256, I = 64, H = 256, O = 64;
constexpr int WSTRIDE = 12;                 // words per kq group: 8 data + 4 pad (16B-aligned, <=2-way banks)
constexpr int HWORDS  = 15 * WSTRIDE + 8;   // 188 words per h buffer

__device__ __forceinline__ half2v pkrtz(float a, float b) {
  return __builtin_bit_cast(half2v, __builtin_amdgcn_cvt_pkrtz(a, b));
}

#if defined(__has_builtin)
#if __has_builtin(__builtin_amdgcn_fdot2)
__device__ __forceinline__ float fdot2(half2v a, half2v b, float c) {
  typedef _Float16 fdot_t __attribute__((ext_vector_type(2)));
  return __builtin_amdgcn_fdot2(__builtin_bit_cast(fdot_t, a),
                                __builtin_bit_cast(fdot_t, b), c, false);
}
#define HAVE_FDOT2 1
#endif
#endif
#ifndef HAVE_FDOT2
__device__ __forceinline__ float fdot2(half2v a, half2v b, float c) {
  return fmaf((float)a.x, (float)b.x, fmaf((float)a.y, (float)b.y, c));
}
#endif

// 16-lane-row sum via DPP row rotations. BUILTIN form only: the compiler's
// hazard recognizer must see these ops (R6's inline-asm v_add_f32_dpp chain
// violated the VALU->DPP wait-state rule and read stale registers).
template <int CTRL>
__device__ __forceinline__ float ror_add(float v) {
  int r = __builtin_amdgcn_update_dpp(0, __float_as_int(v), CTRL, 0xF, 0xF, true);
  return v + __int_as_float(r);
}
__device__ __forceinline__ float red16(float v) {
  v = ror_add<0x121>(v);  // row_ror:1
  v = ror_add<0x122>(v);  // row_ror:2
  v = ror_add<0x124>(v);  // row_ror:4
  v = ror_add<0x128>(v);  // row_ror:8
  return v;
}

// 1024 threads/block, one block per batch row, one barrier per step.
// kq = tid&15 owns k-range [kq*16, kq*16+16); jg = tid>>4 owns h-rows
// jg*4..+3 and y-row jg. Weights live as 48 half2 VGPRs. h is stored in LDS
// as half2 words (word W = (h[2W], h[2W+1])) in a padded layout:
// word W at LDS index (W>>3)*WSTRIDE + (W&7).
__global__ __launch_bounds__(1024) void rnn_fused(
    const float* __restrict__ xin,   // [T,NB,I]
    const float* __restrict__ Wih,   // [H,I]
    const float* __restrict__ Whh,   // [H,H]
    const float* __restrict__ Who,   // [O,H]
    float* __restrict__ out)         // [T*NB*O] ++ [NB*H]
{
  const int b   = blockIdx.x;
  const int tid = threadIdx.x;
  const int kq  = tid & 15;
  const int jg  = tid >> 4;
  const bool kb1 = (kq & 1) != 0;
  const bool kb2 = (kq & 2) != 0;

  __shared__ __align__(16) uint32_t hbuf[2][HWORDS];

  // ---- resident weights as half2 (48 VGPRs) ----
  half2v whhp[32];
#pragma unroll
  for (int jj = 0; jj < 4; ++jj) {
    const float* r = Whh + (size_t)(jg * 4 + jj) * H + kq * 16;
#pragma unroll
    for (int c = 0; c < 4; ++c) {
      float4 v = *reinterpret_cast<const float4*>(r + c * 4);
      whhp[jj * 8 + c * 2]     = pkrtz(v.x, v.y);
      whhp[jj * 8 + c * 2 + 1] = pkrtz(v.z, v.w);
    }
  }
  half2v wihp[8];
#pragma unroll
  for (int jj = 0; jj < 4; ++jj) {
    float4 v = *reinterpret_cast<const float4*>(Wih + (size_t)(jg * 4 + jj) * I + kq * 4);
    wihp[jj * 2]     = pkrtz(v.x, v.y);
    wihp[jj * 2 + 1] = pkrtz(v.z, v.w);
  }
  half2v whop[8];
  {
    const float* r = Who + (size_t)jg * H + kq * 16;
#pragma unroll
    for (int c = 0; c < 4; ++c) {
      float4 v = *reinterpret_cast<const float4*>(r + c * 4);
      whop[c * 2]     = pkrtz(v.x, v.y);
      whop[c * 2 + 1] = pkrtz(v.z, v.w);
    }
  }

  // ---- init ----
  if (tid < HWORDS) hbuf[0][tid] = 0u;               // h(-1) = 0
  const float* xg = xin + (size_t)b * I + kq * 4;    // + t*16384 floats
  float4 xrA = *reinterpret_cast<const float4*>(xg); // x(0)
  float4 xrB;
  // odd lanes write h-pair word W = jg*2 + ((kq&3)>>1)
  const int Wl    = jg * 2 + ((kq & 3) >> 1);
  const int wword = (Wl >> 3) * WSTRIDE + (Wl & 7);
  __syncthreads();

#define STEP(SRC, DST, TCUR, XCUR, XNXT, TPRE)                                   \
  {                                                                              \
    const uint4* rp_ = reinterpret_cast<const uint4*>((SRC) + kq * WSTRIDE);     \
    uint4 w0_ = rp_[0];                                                          \
    uint4 w1_ = rp_[1];                                                          \
    XNXT = *reinterpret_cast<const float4*>(xg + ((size_t)(TPRE) << 14));        \
    half2v xp0_ = pkrtz(XCUR.x, XCUR.y);                                         \
    half2v xp1_ = pkrtz(XCUR.z, XCUR.w);                                         \
    float a0_ = fdot2(xp1_, wihp[1], fdot2(xp0_, wihp[0], 0.f));                 \
    float a1_ = fdot2(xp1_, wihp[3], fdot2(xp0_, wihp[2], 0.f));                 \
    float a2_ = fdot2(xp1_, wihp[5], fdot2(xp0_, wihp[4], 0.f));                 \
    float a3_ = fdot2(xp1_, wihp[7], fdot2(xp0_, wihp[6], 0.f));                 \
    float ay_ = 0.f;                                                             \
    half2v hk_[8];                                                               \
    hk_[0] = __builtin_bit_cast(half2v, w0_.x);                                  \
    hk_[1] = __builtin_bit_cast(half2v, w0_.y);                                  \
    hk_[2] = __builtin_bit_cast(half2v, w0_.z);                                  \
    hk_[3] = __builtin_bit_cast(half2v, w0_.w);                                  \
    hk_[4] = __builtin_bit_cast(half2v, w1_.x);                                  \
    hk_[5] = __builtin_bit_cast(half2v, w1_.y);                                  \
    hk_[6] = __builtin_bit_cast(half2v, w1_.z);                                  \
    hk_[7] = __builtin_bit_cast(half2v, w1_.w);                                  \
    _Pragma("unroll")                                                            \
    for (int c = 0; c < 8; ++c) {                                                \
      a0_ = fdot2(hk_[c], whhp[c], a0_);                                         \
      a1_ = fdot2(hk_[c], whhp[8 + c], a1_);                                     \
      a2_ = fdot2(hk_[c], whhp[16 + c], a2_);                                    \
      a3_ = fdot2(hk_[c], whhp[24 + c], a3_);                                    \
      ay_ = fdot2(hk_[c], whop[c], ay_);                                         \
    }                                                                            \
    a0_ = red16(a0_); a1_ = red16(a1_);                                          \
    a2_ = red16(a2_); a3_ = red16(a3_);                                          \
    ay_ = red16(ay_);                                                            \
    float hs_ = kb2 ? (kb1 ? a3_ : a2_) : (kb1 ? a1_ : a0_);                     \
    float e_  = __builtin_amdgcn_exp2f(hs_ * 2.885390081777927f);                \
    float hv_ = fmaf(-2.f, __builtin_amdgcn_rcpf(e_ + 1.f), 1.f);                \
    float nb_ = __int_as_float(__builtin_amdgcn_mov_dpp(                         \
        __float_as_int(hv_), 0x121, 0xF, 0xF, false));                           \
    half2v pk_ = pkrtz(nb_, hv_);                                                \
    if (kb1) (DST)[wword] = __builtin_bit_cast(uint32_t, pk_);                   \
    if (kq == 0 && (TCUR) > 0)                                                   \
      out[((size_t)((TCUR) - 1) * NB + b) * O + jg] = ay_;                       \
    asm volatile("s_waitcnt lgkmcnt(0)\n\ts_barrier" ::: "memory");              \
  }

  for (int t = 0; t < T; t += 2) {
    const int tp = (t + 3 < T) ? (t + 2) : (T - 1);
    STEP(hbuf[0], hbuf[1], t, xrA, xrB, t + 1);
    STEP(hbuf[1], hbuf[0], t + 1, xrB, xrA, tp);
  }
#undef STEP

  // ---- epilogue: y(T-1) from h(T-1) in hbuf[0] ----
  {
    const uint4* rp = reinterpret_cast<const uint4*>(&hbuf[0][kq * WSTRIDE]);
    uint4 w0 = rp[0], w1 = rp[1];
    half2v hk[8];
    hk[0] = __builtin_bit_cast(half2v, w0.x);
    hk[1] = __builtin_bit_cast(half2v, w0.y);
    hk[2] = __builtin_bit_cast(half2v, w0.z);
    hk[3] = __builtin_bit_cast(half2v, w0.w);
    hk[4] = __builtin_bit_cast(half2v, w1.x);
    hk[5] = __builtin_bit_cast(half2v, w1.y);
    hk[6] = __builtin_bit_cast(half2v, w1.z);
    hk[7] = __builtin_bit_cast(half2v, w1.w);
    float ay = 0.f;
#pragma unroll
    for (int c = 0; c < 8; ++c) ay = fdot2(hk[c], whop[c], ay);
    ay = red16(ay);
    if (kq == 0) out[((size_t)(T - 1) * NB + b) * O + jg] = ay;
  }
  // ---- h_last (fp32) ----
  if (tid < 128) {
    uint32_t w = hbuf[0][(tid >> 3) * WSTRIDE + (tid & 7)];
    half2v hh = __builtin_bit_cast(half2v, w);
    float* hl = out + (size_t)T * NB * O + (size_t)b * H + 2 * tid;
    hl[0] = (float)hh.x;
    hl[1] = (float)hh.y;
  }
}

}  // namespace

extern "C" void kernel_launch(void* const* d_in, const int* in_sizes, int n_in,
                              void* d_out, int out_size, void* d_ws, size_t ws_size,
                              hipStream_t stream) {
  const float* xin = (const float*)d_in[0];
  const float* Wih = (const float*)d_in[1];
  const float* Whh = (const float*)d_in[2];
  const float* Who = (const float*)d_in[3];
  float* out = (float*)d_out;
  hipLaunchKernelGGL(rnn_fused, dim3(NB), dim3(1024), 0, stream,
                     xin, Wih, Whh, Who, out);
}

// Round 8
// 2778.810 us; speedup vs baseline: 1.6887x; 1.0465x over previous
//
#include <hip/hip_runtime.h>
#include <math.h>

namespace {

typedef __fp16 half2v __attribute__((ext_vector_type(2)));
static_assert(sizeof(half2v) == 4, "half2v must be 32-bit");

constexpr int T = 4096, NB = 256, I = 64, H = 256, O = 64;
// State s = [h(256); x(64)] as fp16: 320 halfs = 160 words.
// Padded layout: word W -> index (W>>3)*12 + (W&7)  (8 data + 4 pad words
// per group; group stride 48B spreads banks). 20 groups -> 240 words/buffer.
constexpr int SWORDS = 240;

__device__ __forceinline__ half2v pkrtz(float a, float b) {
  return __builtin_bit_cast(half2v, __builtin_amdgcn_cvt_pkrtz(a, b));
}
__device__ __forceinline__ half2v h2bits(uint32_t u) {
  return __builtin_bit_cast(half2v, u);
}
__device__ __forceinline__ float fdot2(half2v a, half2v b, float c) {
  typedef _Float16 fdot_t __attribute__((ext_vector_type(2)));
  return __builtin_amdgcn_fdot2(__builtin_bit_cast(fdot_t, a),
                                __builtin_bit_cast(fdot_t, b), c, false);
}
// BUILTIN DPP only (R6 lesson: inline-asm DPP chains violate wait-state rules).
template <int CTRL>
__device__ __forceinline__ float dpp_add(float v) {
  int r = __builtin_amdgcn_update_dpp(0, __float_as_int(v), CTRL, 0xF, 0xF, true);
  return v + __int_as_float(r);
}
__device__ __forceinline__ float red4(float v) {   // sum over quad of 4 lanes
  v = dpp_add<0x39>(v);  // quad_perm [1,2,3,0]
  v = dpp_add<0x4E>(v);  // quad_perm [2,3,0,1]
  return v;
}
__device__ __forceinline__ float red16(float v) {  // sum over 16-lane row
  v = dpp_add<0x121>(v);
  v = dpp_add<0x122>(v);
  v = dpp_add<0x124>(v);
  v = dpp_add<0x128>(v);
  return v;
}
__device__ __forceinline__ int widx(int W) { return (W >> 3) * 12 + (W & 7); }

// 1024 threads/block, one block per batch row, one barrier per step.
// h mapping: j = tid>>2 (h-row), q = tid&3 (state-quarter, 80 elems).
// y mapping: o = tid>>4, kq = tid&15 (16 h elems).
__global__ __launch_bounds__(1024) void rnn_fused(
    const float* __restrict__ xin,   // [T,NB,I]
    const float* __restrict__ Wih,   // [H,I]
    const float* __restrict__ Whh,   // [H,H]
    const float* __restrict__ Who,   // [O,H]
    float* __restrict__ out)         // [T*NB*O] ++ [NB*H]
{
  const int b   = blockIdx.x;
  const int tid = threadIdx.x;
  const int j   = tid >> 2;
  const int q   = tid & 3;
  const int o   = tid >> 4;
  const int kq  = tid & 15;

  __shared__ __align__(16) uint32_t sbuf[2][SWORDS];

  // ---- resident weights: W' = [Whh | Wih] row j, cols [80q, 80q+80) ----
  half2v wcat[40];
#pragma unroll
  for (int m = 0; m < 40; ++m) {
    const int k0 = 80 * q + 2 * m;
    const float* src = (k0 < H) ? (Whh + (size_t)j * H + k0)
                                : (Wih + (size_t)j * I + (k0 - H));
    float2 v = *reinterpret_cast<const float2*>(src);
    wcat[m] = pkrtz(v.x, v.y);
  }
  half2v whop[8];
#pragma unroll
  for (int c = 0; c < 8; ++c) {
    float2 v = *reinterpret_cast<const float2*>(Who + (size_t)o * H + 16 * kq + 2 * c);
    whop[c] = pkrtz(v.x, v.y);
  }

  // ---- init: buf0 = [h(-1)=0 ; x(0)], xcur = x(1) ----
  if (tid < 192) sbuf[0][tid] = 0u;   // h region (idx 0..187) + its pads
  const float* xg = xin + (size_t)b * I + 2 * (tid & 31);
  const int xw = widx(128 + (tid & 31));
  float2 xcur = make_float2(0.f, 0.f);
  if (tid < 32) {
    float2 x0 = *reinterpret_cast<const float2*>(xg);
    sbuf[0][xw] = __builtin_bit_cast(uint32_t, pkrtz(x0.x, x0.y));
    xcur = *reinterpret_cast<const float2*>(xg + NB * I);
  }
  const int hwbyte = widx(j >> 1) * 4 + (j & 1) * 2;  // byte offset of h_j
  const int ybase  = b * O + o;
  __syncthreads();

  auto step = [&](const uint32_t* SRC, uint32_t* DST, int TCUR) {
    // ---- deferred y(TCUR-1) = Who @ h(TCUR-1) ----
    const uint4* yrp = reinterpret_cast<const uint4*>(SRC + kq * 12);
    uint4 yw0 = yrp[0], yw1 = yrp[1];
    float ay = fdot2(h2bits(yw0.x), whop[0], 0.f);
    ay = fdot2(h2bits(yw0.y), whop[1], ay);
    ay = fdot2(h2bits(yw0.z), whop[2], ay);
    ay = fdot2(h2bits(yw0.w), whop[3], ay);
    ay = fdot2(h2bits(yw1.x), whop[4], ay);
    ay = fdot2(h2bits(yw1.y), whop[5], ay);
    ay = fdot2(h2bits(yw1.z), whop[6], ay);
    ay = fdot2(h2bits(yw1.w), whop[7], ay);
    ay = red16(ay);
    if (kq == 0 && TCUR > 0)
      out[((size_t)(TCUR - 1) << 14) + ybase] = ay;

    // ---- h(TCUR) row j: dot over state quarter [80q, 80q+80) ----
    float a0 = 0.f, a1 = 0.f;
    const uint32_t* hrp = SRC + 60 * q;   // word-group base (5q)*12
#pragma unroll
    for (int g = 0; g < 5; ++g) {
      const uint4* rp = reinterpret_cast<const uint4*>(hrp + g * 12);
      uint4 u0 = rp[0], u1 = rp[1];
      a0 = fdot2(h2bits(u0.x), wcat[8 * g + 0], a0);
      a1 = fdot2(h2bits(u0.y), wcat[8 * g + 1], a1);
      a0 = fdot2(h2bits(u0.z), wcat[8 * g + 2], a0);
      a1 = fdot2(h2bits(u0.w), wcat[8 * g + 3], a1);
      a0 = fdot2(h2bits(u1.x), wcat[8 * g + 4], a0);
      a1 = fdot2(h2bits(u1.y), wcat[8 * g + 5], a1);
      a0 = fdot2(h2bits(u1.z), wcat[8 * g + 6], a0);
      a1 = fdot2(h2bits(u1.w), wcat[8 * g + 7], a1);
    }
    float s = red4(a0 + a1);
    // tanh(s) = 1 - 2/(exp2(s*2/ln2)+1); saturates correctly at +-inf args.
    float e  = __builtin_amdgcn_exp2f(s * 2.885390081777927f);
    float hv = fmaf(-2.f, __builtin_amdgcn_rcpf(e + 1.f), 1.f);
    if (q == 0)
      *reinterpret_cast<__fp16*>(reinterpret_cast<char*>(DST) + hwbyte) = (__fp16)hv;

    // ---- stage x(TCUR+1) into DST, prefetch x(TCUR+2) ----
    if (tid < 32) {
      DST[xw] = __builtin_bit_cast(uint32_t, pkrtz(xcur.x, xcur.y));
      const int tnx = (TCUR + 2 < T) ? (TCUR + 2) : (T - 1);
      xcur = *reinterpret_cast<const float2*>(xg + (size_t)tnx * (NB * I));
    }
    // barrier without vmcnt drain: x-load and y-store float across it
    asm volatile("s_waitcnt lgkmcnt(0)\n\ts_barrier" ::: "memory");
  };

  for (int t = 0; t < T; t += 2) {
    step(sbuf[0], sbuf[1], t);
    step(sbuf[1], sbuf[0], t + 1);
  }

  // ---- epilogue: y(T-1) from sbuf[0] ----
  {
    const uint4* yrp = reinterpret_cast<const uint4*>(&sbuf[0][kq * 12]);
    uint4 yw0 = yrp[0], yw1 = yrp[1];
    float ay = fdot2(h2bits(yw0.x), whop[0], 0.f);
    ay = fdot2(h2bits(yw0.y), whop[1], ay);
    ay = fdot2(h2bits(yw0.z), whop[2], ay);
    ay = fdot2(h2bits(yw0.w), whop[3], ay);
    ay = fdot2(h2bits(yw1.x), whop[4], ay);
    ay = fdot2(h2bits(yw1.y), whop[5], ay);
    ay = fdot2(h2bits(yw1.z), whop[6], ay);
    ay = fdot2(h2bits(yw1.w), whop[7], ay);
    ay = red16(ay);
    if (kq == 0) out[((size_t)(T - 1) << 14) + ybase] = ay;
  }
  // ---- h_last (fp32) ----
  if (tid < H) {
    uint32_t w = sbuf[0][widx(tid >> 1)];
    unsigned short hb = (tid & 1) ? (unsigned short)(w >> 16)
                                  : (unsigned short)(w & 0xFFFFu);
    __fp16 hh = __builtin_bit_cast(__fp16, hb);
    out[(size_t)T * NB * O + (size_t)b * H + tid] = (float)hh;
  }
}

}  // namespace

extern "C" void kernel_launch(void* const* d_in, const int* in_sizes, int n_in,
                              void* d_out, int out_size, void* d_ws, size_t ws_size,
                              hipStream_t stream) {
  const float* xin = (const float*)d_in[0];
  const float* Wih = (const float*)d_in[1];
  const float* Whh = (const float*)d_in[2];
  const float* Who = (const float*)d_in[3];
  float* out = (float*)d_out;
  hipLaunchKernelGGL(rnn_fused, dim3(NB), dim3(1024), 0, stream,
                     xin, Wih, Whh, Who, out);
}